// Round 5
// baseline (86.279 us; speedup 1.0000x reference)
//
#include <hip/hip_runtime.h>

#define HH 320
#define WW 320
#define NIMG 8      // B(4) * channels(2)
#define BIGF 1.0e5f

// ---- Kernel 1: vertical 1D distance, chunked parallel scan, float2 loads ----
// (unchanged — verified absmax 0 in rounds 2-3)
#define TW  16
#define NCH 32
#define CH  10

__global__ __launch_bounds__(512) void edt_vert(const float* __restrict__ in,
                                                float* __restrict__ g2) {
    int wl = threadIdx.x;            // 0..15 column within tile
    int ch = threadIdx.y;            // 0..31 h-chunk
    int b  = blockIdx.x / 20;
    int wt = blockIdx.x % 20;
    int w  = wt * TW + wl;
    int h0 = ch * CH;

    const float2* ip = (const float2*)in + (size_t)(b * HH + h0) * WW + w;
    float2 v[CH];
    #pragma unroll
    for (int k = 0; k < CH; ++k) v[k] = ip[(size_t)k * WW];

    unsigned m0 = 0, m1 = 0;
    #pragma unroll
    for (int k = 0; k < CH; ++k) {
        if ((1.0f - v[k].x) * 127.5f < 1.0f) m0 |= 1u << k;  // uint8 restore == 0
        if ((1.0f - v[k].y) * 127.5f < 1.0f) m1 |= 1u << k;
    }

    __shared__ float sL[2][NCH][TW], sN[2][NCH][TW];
    sL[0][ch][wl] = m0 ? (float)(h0 + 31 - __clz((int)m0)) : -1.0e9f;
    sL[1][ch][wl] = m1 ? (float)(h0 + 31 - __clz((int)m1)) : -1.0e9f;
    sN[0][ch][wl] = m0 ? (float)(h0 + __ffs((int)m0) - 1)  :  1.0e9f;
    sN[1][ch][wl] = m1 ? (float)(h0 + __ffs((int)m1) - 1)  :  1.0e9f;
    __syncthreads();

    float L0 = -1.0e9f, L1 = -1.0e9f, N0 = 1.0e9f, N1 = 1.0e9f;
    for (int cc = 0; cc < NCH; ++cc) {
        float a0 = sL[0][cc][wl], a1 = sL[1][cc][wl];
        float b0 = sN[0][cc][wl], b1 = sN[1][cc][wl];
        if (cc < ch) { L0 = fmaxf(L0, a0); L1 = fmaxf(L1, a1); }
        if (cc > ch) { N0 = fminf(N0, b0); N1 = fminf(N1, b1); }
    }

    float gd0[CH], gd1[CH];
    float r0 = L0, r1 = L1;
    #pragma unroll
    for (int k = 0; k < CH; ++k) {
        float fh = (float)(h0 + k);
        if (m0 & (1u << k)) r0 = fh;
        if (m1 & (1u << k)) r1 = fh;
        gd0[k] = fh - r0;
        gd1[k] = fh - r1;
    }
    float* gp0 = g2 + ((size_t)(b * 2 + 0) * HH + h0) * WW + w;
    float* gp1 = g2 + ((size_t)(b * 2 + 1) * HH + h0) * WW + w;
    r0 = N0; r1 = N1;
    #pragma unroll
    for (int k = CH - 1; k >= 0; --k) {
        float fh = (float)(h0 + k);
        if (m0 & (1u << k)) r0 = fh;
        if (m1 & (1u << k)) r1 = fh;
        float g0 = fminf(fminf(gd0[k], r0 - fh), BIGF);
        float g1 = fminf(fminf(gd1[k], r1 - fh), BIGF);
        gp0[(size_t)k * WW] = g0 * g0;
        gp1[(size_t)k * WW] = g1 * g1;
    }
}

// ---- Kernel 2: exact horizontal lower envelope with chunk pruning ----
// Block = 4 waves; wave wv handles row h=2*hp+(wv>>1), channel c=wv&1.
// d2v is kept in the SHIFTED domain (d2 - j^2); all pruning bounds compare in
// the ACTUAL domain via thr = d2v + j^2 (round-4 bug was comparing across
// domains). Skip chunk iff gap^2 + min_g2[chunk] >= thr for all lanes (exact,
// conservative); terminate side iff gap^2 >= thr for all lanes (gap monotone
// in ring radius). Epilogue: d2 staged in LDS, cooperative coalesced float4
// stores of both rows x all 6 channels.
__global__ __launch_bounds__(256) void edt_horiz(const float* __restrict__ g2,
                                                 float* __restrict__ out) {
    int wv   = threadIdx.x >> 6;
    int lane = threadIdx.x & 63;
    int b  = blockIdx.x / 160;
    int hp = blockIdx.x % 160;
    int hh = wv >> 1;                 // which of the two rows
    int c  = wv & 1;                  // channel
    int row = (2 * b + c) * HH + (2 * hp + hh);   // g2 row index

    __shared__ __align__(16) float sa[4][WW];     // a[x] = x^2 + g2[x], per wave
    __shared__ float scm[4][10];                  // per-32-chunk min of g2
    __shared__ float sd2[2][2][WW];               // [row'][channel][j] = actual d2

    const float* grow = g2 + (size_t)row * WW;
    #pragma unroll
    for (int m = 0; m < 5; ++m) {
        int x = lane + 64 * m;
        float g = grow[x];
        float fx = (float)x;
        sa[wv][x] = fmaf(fx, fx, g);
        float v = g;                               // min over 32-lane half
        v = fminf(v, __shfl_xor(v, 1));
        v = fminf(v, __shfl_xor(v, 2));
        v = fminf(v, __shfl_xor(v, 4));
        v = fminf(v, __shfl_xor(v, 8));
        v = fminf(v, __shfl_xor(v, 16));
        if ((lane & 31) == 0) scm[wv][2 * m + (lane >> 5)] = v;
    }
    // sa/scm are wave-private; same-wave LDS ordering suffices

    const float4* sv = (const float4*)sa[wv];
    float d2v[5], n2j[5];
    #pragma unroll
    for (int m = 0; m < 5; ++m) {
        d2v[m] = 3.4e38f;
        n2j[m] = -2.0f * (float)(lane + 64 * m);
    }

    auto scanChunk = [&](int m, int ck) {          // 32 x's of chunk ck, group m
        int q0 = ck * 8;
        #pragma unroll
        for (int u = 0; u < 8; u += 2) {
            float4 f0 = sv[q0 + u];                // uniform addr -> broadcast
            float4 f1 = sv[q0 + u + 1];
            float xb = (float)(ck * 32 + 4 * u);
            float av[8] = {f0.x, f0.y, f0.z, f0.w, f1.x, f1.y, f1.z, f1.w};
            #pragma unroll
            for (int k = 0; k < 8; k += 2) {
                float t0 = fmaf(n2j[m], xb + (float)k,       av[k]);
                float t1 = fmaf(n2j[m], xb + (float)(k + 1), av[k + 1]);
                d2v[m] = fminf(d2v[m], fminf(t0, t1));
            }
        }
    };

    // own chunks: full coverage of x in [64m, 64m+64)  (includes x == j)
    #pragma unroll
    for (int m = 0; m < 5; ++m) { scanChunk(m, 2 * m); scanChunk(m, 2 * m + 1); }

    // ring phase: outward with exact bounds in the ACTUAL-d2 domain
    for (int m = 0; m < 5; ++m) {
        float fj  = (float)(lane + 64 * m);
        float fj2 = fj * fj;
        bool goL = (m > 0), goR = (m < 4);
        for (int r = 1; r < 10 && (goL || goR); ++r) {
            int cl = 2 * m - r, cr = 2 * m + 1 + r;
            if (goL) {
                if (cl < 0) goL = false;
                else {
                    float thr = d2v[m] + fj2;                 // current true d2
                    float gap = fj - (float)(32 * cl + 31);   // >= 1, exact int
                    float bb = gap * gap;
                    if (!__any(bb < thr)) goL = false;        // monotone stop
                    else if (__any(bb + scm[wv][cl] < thr)) scanChunk(m, cl);
                }
            }
            if (goR) {
                if (cr > 9) goR = false;
                else {
                    float thr = d2v[m] + fj2;
                    float gap = (float)(32 * cr) - fj;
                    float bb = gap * gap;
                    if (!__any(bb < thr)) goR = false;
                    else if (__any(bb + scm[wv][cr] < thr)) scanChunk(m, cr);
                }
            }
        }
    }

    // stage actual d2 = d2v + j^2 (conflict-free stride-1 writes)
    #pragma unroll
    for (int m = 0; m < 5; ++m) {
        float fj = (float)(lane + 64 * m);
        sd2[hh][c][lane + 64 * m] = fmaf(fj, fj, d2v[m]);
    }
    __syncthreads();

    // cooperative coalesced write: 2 rows x 320 j x 6 ch = 960 float4
    float* obase = out + (size_t)(b * HH + 2 * hp) * WW * 6;
    for (int q = threadIdx.x; q < 960; q += 256) {
        int D = 4 * q;
        int hh2 = D / 1920;
        int rr = D - 1920 * hh2;
        float vals[4];
        #pragma unroll
        for (int e = 0; e < 4; ++e) {
            int idx = rr + e;
            int jj = idx / 6;
            int cs = idx - 6 * jj;                 // output channel 0..5
            int c2 = (cs >= 3) ? 1 : 0;
            int s  = cs - 3 * c2;
            float dd = sd2[hh2][c2][jj];
            float co = (s == 0) ? (1.0f / 81.92f)
                     : (s == 1) ? (1.0f / 1310.72f)
                                : (1.0f / 5242.88f);
            vals[e] = __expf(-dd * co);
        }
        float4 o = {vals[0], vals[1], vals[2], vals[3]};
        *(float4*)(obase + D) = o;
    }
}

extern "C" void kernel_launch(void* const* d_in, const int* in_sizes, int n_in,
                              void* d_out, int out_size, void* d_ws, size_t ws_size,
                              hipStream_t stream) {
    const float* in = (const float*)d_in[0];
    float* out = (float*)d_out;
    float* g2 = (float*)d_ws;   // NIMG*H*W floats = 3.27 MB scratch

    edt_vert<<<4 * 20, dim3(TW, NCH), 0, stream>>>(in, g2);
    edt_horiz<<<4 * 160, 256, 0, stream>>>(g2, out);
}

// Round 6
// 74.028 us; speedup vs baseline: 1.1655x; 1.1655x over previous
//
#include <hip/hip_runtime.h>

#define HH 320
#define WW 320
#define NIMG 8      // B(4) * channels(2)
#define BIGF 1.0e5f

// ---- Kernel 1: vertical 1D distance, chunked parallel scan, float2 loads ----
// (unchanged — verified absmax 0 in rounds 2-5)
#define TW  16
#define NCH 32
#define CH  10

__global__ __launch_bounds__(512) void edt_vert(const float* __restrict__ in,
                                                float* __restrict__ g2) {
    int wl = threadIdx.x;            // 0..15 column within tile
    int ch = threadIdx.y;            // 0..31 h-chunk
    int b  = blockIdx.x / 20;
    int wt = blockIdx.x % 20;
    int w  = wt * TW + wl;
    int h0 = ch * CH;

    const float2* ip = (const float2*)in + (size_t)(b * HH + h0) * WW + w;
    float2 v[CH];
    #pragma unroll
    for (int k = 0; k < CH; ++k) v[k] = ip[(size_t)k * WW];

    unsigned m0 = 0, m1 = 0;
    #pragma unroll
    for (int k = 0; k < CH; ++k) {
        if ((1.0f - v[k].x) * 127.5f < 1.0f) m0 |= 1u << k;  // uint8 restore == 0
        if ((1.0f - v[k].y) * 127.5f < 1.0f) m1 |= 1u << k;
    }

    __shared__ float sL[2][NCH][TW], sN[2][NCH][TW];
    sL[0][ch][wl] = m0 ? (float)(h0 + 31 - __clz((int)m0)) : -1.0e9f;
    sL[1][ch][wl] = m1 ? (float)(h0 + 31 - __clz((int)m1)) : -1.0e9f;
    sN[0][ch][wl] = m0 ? (float)(h0 + __ffs((int)m0) - 1)  :  1.0e9f;
    sN[1][ch][wl] = m1 ? (float)(h0 + __ffs((int)m1) - 1)  :  1.0e9f;
    __syncthreads();

    float L0 = -1.0e9f, L1 = -1.0e9f, N0 = 1.0e9f, N1 = 1.0e9f;
    for (int cc = 0; cc < NCH; ++cc) {
        float a0 = sL[0][cc][wl], a1 = sL[1][cc][wl];
        float b0 = sN[0][cc][wl], b1 = sN[1][cc][wl];
        if (cc < ch) { L0 = fmaxf(L0, a0); L1 = fmaxf(L1, a1); }
        if (cc > ch) { N0 = fminf(N0, b0); N1 = fminf(N1, b1); }
    }

    float gd0[CH], gd1[CH];
    float r0 = L0, r1 = L1;
    #pragma unroll
    for (int k = 0; k < CH; ++k) {
        float fh = (float)(h0 + k);
        if (m0 & (1u << k)) r0 = fh;
        if (m1 & (1u << k)) r1 = fh;
        gd0[k] = fh - r0;
        gd1[k] = fh - r1;
    }
    float* gp0 = g2 + ((size_t)(b * 2 + 0) * HH + h0) * WW + w;
    float* gp1 = g2 + ((size_t)(b * 2 + 1) * HH + h0) * WW + w;
    r0 = N0; r1 = N1;
    #pragma unroll
    for (int k = CH - 1; k >= 0; --k) {
        float fh = (float)(h0 + k);
        if (m0 & (1u << k)) r0 = fh;
        if (m1 & (1u << k)) r1 = fh;
        float g0 = fminf(fminf(gd0[k], r0 - fh), BIGF);
        float g1 = fminf(fminf(gd1[k], r1 - fh), BIGF);
        gp0[(size_t)k * WW] = g0 * g0;
        gp1[(size_t)k * WW] = g1 * g1;
    }
}

// ---- Kernel 2: blind exact lower envelope, register-double-buffered ----
// Block = 4 waves; wave wv handles row h=2*hp+(wv>>1), channel c=wv&1.
// No pruning (round 5 showed ballot overhead > saved work at W=320).
// a[x]=x^2+g2[x] in LDS; fully-unrolled loop over 10 tiles of 64 x's, next
// tile's 8 float4 issued before computing current tile (~960 VALU cyc of
// cover >> 120 cyc LDS latency). d2 = min_x fma(-2j, x, a[x]) + j^2 — all
// exact integers < 2^24 in the non-capped region -> bit-exact (verified R3/R5).
// Epilogue: cooperative fully-coalesced float4 stores (verified R5).
__global__ __launch_bounds__(256) void edt_horiz(const float* __restrict__ g2,
                                                 float* __restrict__ out) {
    int wv   = threadIdx.x >> 6;
    int lane = threadIdx.x & 63;
    int b  = blockIdx.x / 160;
    int hp = blockIdx.x % 160;
    int hh = wv >> 1;                 // which of the two rows
    int c  = wv & 1;                  // channel
    int row = (2 * b + c) * HH + (2 * hp + hh);   // g2 row index

    __shared__ __align__(16) float sa[4][WW];     // a[x] = x^2 + g2[x], per wave
    __shared__ float sd2[2][2][WW];               // [row'][channel][j] = actual d2

    const float* grow = g2 + (size_t)row * WW;
    #pragma unroll
    for (int m = 0; m < 5; ++m) {
        int x = lane + 64 * m;
        float fx = (float)x;
        sa[wv][x] = fmaf(fx, fx, grow[x]);
    }
    // sa is wave-private; same-wave LDS write->read ordering suffices

    const float4* sv = (const float4*)sa[wv];
    float d2v[5], n2j[5];
    #pragma unroll
    for (int m = 0; m < 5; ++m) {
        d2v[m] = 3.4e38f;
        n2j[m] = -2.0f * (float)(lane + 64 * m);
    }

    float4 cur[8], nxt[8];
    #pragma unroll
    for (int q = 0; q < 8; ++q) cur[q] = sv[q];   // tile 0 (broadcast b128)
    #pragma unroll
    for (int t = 0; t < 10; ++t) {
        if (t < 9) {
            #pragma unroll
            for (int q = 0; q < 8; ++q) nxt[q] = sv[8 * (t + 1) + q];
        }
        #pragma unroll
        for (int q = 0; q < 8; ++q) {
            float a0 = cur[q].x, a1 = cur[q].y, a2 = cur[q].z, a3 = cur[q].w;
            float x0 = (float)(32 * t + 4 * q);
            #pragma unroll
            for (int m = 0; m < 5; ++m) {
                float t0 = fmaf(n2j[m], x0,        a0);
                float t1 = fmaf(n2j[m], x0 + 1.0f, a1);
                float t2 = fmaf(n2j[m], x0 + 2.0f, a2);
                float t3 = fmaf(n2j[m], x0 + 3.0f, a3);
                // -> v_min + v_min + v_min3
                d2v[m] = fminf(fminf(d2v[m], fminf(t0, t1)), fminf(t2, t3));
            }
        }
        #pragma unroll
        for (int q = 0; q < 8; ++q) cur[q] = nxt[q];   // elided by full unroll
    }

    // stage actual d2 = d2v + j^2 (conflict-free stride-1 writes)
    #pragma unroll
    for (int m = 0; m < 5; ++m) {
        float fj = (float)(lane + 64 * m);
        sd2[hh][c][lane + 64 * m] = fmaf(fj, fj, d2v[m]);
    }
    __syncthreads();

    // cooperative coalesced write: 2 rows x 320 j x 6 ch = 960 float4
    float* obase = out + (size_t)(b * HH + 2 * hp) * WW * 6;
    for (int q = threadIdx.x; q < 960; q += 256) {
        int D = 4 * q;
        int hh2 = D / 1920;
        int rr = D - 1920 * hh2;
        float vals[4];
        #pragma unroll
        for (int e = 0; e < 4; ++e) {
            int idx = rr + e;
            int jj = idx / 6;
            int cs = idx - 6 * jj;                 // output channel 0..5
            int c2 = (cs >= 3) ? 1 : 0;
            int s  = cs - 3 * c2;
            float dd = sd2[hh2][c2][jj];
            float co = (s == 0) ? (1.0f / 81.92f)
                     : (s == 1) ? (1.0f / 1310.72f)
                                : (1.0f / 5242.88f);
            vals[e] = __expf(-dd * co);
        }
        float4 o = {vals[0], vals[1], vals[2], vals[3]};
        *(float4*)(obase + D) = o;
    }
}

extern "C" void kernel_launch(void* const* d_in, const int* in_sizes, int n_in,
                              void* d_out, int out_size, void* d_ws, size_t ws_size,
                              hipStream_t stream) {
    const float* in = (const float*)d_in[0];
    float* out = (float*)d_out;
    float* g2 = (float*)d_ws;   // NIMG*H*W floats = 3.27 MB scratch

    edt_vert<<<4 * 20, dim3(TW, NCH), 0, stream>>>(in, g2);
    edt_horiz<<<4 * 160, 256, 0, stream>>>(g2, out);
}